// Round 6
// baseline (364.107 us; speedup 1.0000x reference)
//
#include <hip/hip_runtime.h>

#define B_ 4
#define S_ 2048
#define D_ 1024
#define E_ 1024
#define H_ 16
#define HD_ 64
#define SCALE 0.125f
#define LOG2E 1.44269504f
#define C1_ (SCALE * LOG2E)

typedef __bf16 bf16;
typedef __bf16 bf16x8 __attribute__((ext_vector_type(8)));
typedef __bf16 bf16x4 __attribute__((ext_vector_type(4)));
typedef float f32x4 __attribute__((ext_vector_type(4)));
typedef _Float16 f16x8 __attribute__((ext_vector_type(8)));
typedef _Float16 f16x4 __attribute__((ext_vector_type(4)));

static __device__ __forceinline__ f32x4 mfma16(bf16x8 a, bf16x8 b, f32x4 c) {
  return __builtin_amdgcn_mfma_f32_16x16x32_bf16(a, b, c, 0, 0, 0);
}

typedef __attribute__((address_space(3))) void lvoid;
typedef const __attribute__((address_space(1))) void gvoid;
static __device__ __forceinline__ void gload16(const void* g, void* l) {
  __builtin_amdgcn_global_load_lds((gvoid*)g, (lvoid*)l, 16, 0, 0);
}

// raw 2^x (input already scaled by log2e)
static __device__ __forceinline__ float exp2a(float x) {
  float r;
  asm("v_exp_f32 %0, %1" : "=v"(r) : "v"(x));
  return r;
}

// 3-bit row swizzle: spreads both natural and permuted row-reads over 8 slots
static __device__ __forceinline__ int rsw(int row) {
  return (row & 3) | (((row >> 3) & 1) << 2);
}

// ---- elementwise f32 -> bf16 convert (4 per thread) ----
__global__ void k_cvt(const float* __restrict__ in, bf16* __restrict__ out, int n4) {
  int i = blockIdx.x * 256 + threadIdx.x;
  if (i >= n4) return;
  float4 v = reinterpret_cast<const float4*>(in)[i];
  bf16x4 o = { (bf16)v.x, (bf16)v.y, (bf16)v.z, (bf16)v.w };
  reinterpret_cast<bf16x4*>(out)[i] = o;
}

// ---- mask f32 -> fp16, pre-scaled by log2e (softmax is shift-invariant, no m-hat) ----
__global__ void k_cvt16(const float* __restrict__ in, _Float16* __restrict__ out, int n4) {
  int i = blockIdx.x * 256 + threadIdx.x;
  if (i >= n4) return;
  float4 v = reinterpret_cast<const float4*>(in)[i];
  f16x4 o = { (_Float16)(v.x * LOG2E), (_Float16)(v.y * LOG2E),
              (_Float16)(v.z * LOG2E), (_Float16)(v.w * LOG2E) };
  reinterpret_cast<f16x4*>(out)[i] = o;
}

// ---- QKV GEMM, m97 structure: 128x128 tile, LDS-staged via global_load_lds ----
__global__ __launch_bounds__(256) void k_qkv(const bf16* __restrict__ xb,
                                             const bf16* __restrict__ wb,
                                             const float* __restrict__ qkvb,
                                             bf16* __restrict__ Qw,
                                             bf16* __restrict__ Kw,
                                             bf16* __restrict__ Vtw) {
  __shared__ __align__(16) bf16 lA[128 * 32];
  __shared__ __align__(16) bf16 lB[128 * 32];
  const int tid = threadIdx.x, lane = tid & 63, wv = tid >> 6;
  const int u = lane >> 4, c = lane & 15;
  const int wr = wv >> 1, wc = wv & 1;
  const int m0 = blockIdx.y * 128;
  const int n0 = blockIdx.x * 128;
  const int sr = tid >> 2, sk = (tid & 3) * 8;
  const bf16* gA = xb + (size_t)(m0 + sr) * D_ + sk;
  const bf16* gB = wb + (size_t)(n0 + sr) * D_ + sk;
  bf16* lpA = lA + wv * 512;
  bf16* lpB = lB + wv * 512;
  f32x4 acc[4][4] = {};
  for (int k0 = 0; k0 < D_; k0 += 32) {
    gload16(gA + k0, lpA);
    gload16(gA + 64 * D_ + k0, lpA + 2048);
    gload16(gB + k0, lpB);
    gload16(gB + 64 * D_ + k0, lpB + 2048);
    __syncthreads();
    bf16x8 af[4], bfr[4];
#pragma unroll
    for (int m = 0; m < 4; ++m)
      af[m] = *(const bf16x8*)(lA + (wr * 64 + m * 16 + c) * 32 + u * 8);
#pragma unroll
    for (int n = 0; n < 4; ++n)
      bfr[n] = *(const bf16x8*)(lB + (wc * 64 + n * 16 + c) * 32 + u * 8);
#pragma unroll
    for (int m = 0; m < 4; ++m)
#pragma unroll
      for (int n = 0; n < 4; ++n)
        acc[m][n] = mfma16(af[m], bfr[n], acc[m][n]);
    __syncthreads();
  }
#pragma unroll
  for (int n = 0; n < 4; ++n) {
    int nn = n0 + wc * 64 + n * 16 + c;
    float bias = qkvb[nn];
    int h = nn / 192;
    int rem = nn - h * 192;
#pragma unroll
    for (int m = 0; m < 4; ++m) {
#pragma unroll
      for (int r = 0; r < 4; ++r) {
        int q = m0 + wr * 64 + m * 16 + 4 * u + r;
        int bb = q >> 11, s = q & 2047;
        bf16 v = (bf16)(acc[m][n][r] + bias);
        if (rem < 64)       Qw[((bb * H_ + h) * S_ + s) * HD_ + rem] = v;
        else if (rem < 128) Kw[((bb * H_ + h) * S_ + s) * HD_ + (rem - 64)] = v;
        else                Vtw[((bb * H_ + h) * HD_ + (rem - 128)) * S_ + s] = v;
      }
    }
  }
}

// ---- PV, swapped QK^T + permuted K rows. 4 waves x 2 q-groups (32 q-rows/wave)
// — exact R1 structure (proven 118 us): staging mid-tile, mask prefetch, exp,
// PV MFMAs, one __syncthreads per tile. 4 independent barrier domains per CU.
#define PV_TILE2(HC, HN, BS, KT, PF)                                          \
  {                                                                           \
    f32x4 sA[4], sB[4];                                                       \
    _Pragma("unroll")                                                         \
    for (int f = 0; f < 4; ++f) {                                             \
      int rk = 32 * (f & 1) + 8 * (c >> 2) + 4 * (f >> 1) + (c & 3);          \
      int sw = rsw(rk);                                                       \
      bf16x8 k0 = *(const bf16x8*)&kl[BS][rk * 64 + ((u ^ sw) * 8)];          \
      bf16x8 k1 = *(const bf16x8*)&kl[BS][rk * 64 + (((4 + u) ^ sw) * 8)];    \
      f32x4 a = {};                                                           \
      a = mfma16(k0, aqA0, a);                                                \
      a = mfma16(k1, aqA1, a);                                                \
      sA[f] = a;                                                              \
      f32x4 bb2 = {};                                                         \
      bb2 = mfma16(k0, aqB0, bb2);                                            \
      bb2 = mfma16(k1, aqB1, bb2);                                            \
      sB[f] = bb2;                                                            \
    }                                                                         \
    if (PF) {                                                                 \
      const bf16* ksrc = Kb + (size_t)((KT) + 1) * 64 * HD_;                  \
      gload16(ksrc + ksw1, (bf16*)kl[(BS) ^ 1] + wv * 512);                   \
      gload16(ksrc + ksw2, (bf16*)kl[(BS) ^ 1] + 2048 + wv * 512);            \
      const bf16* vsrc = Vb + (size_t)((KT) + 1) * 64;                        \
      gload16(vsrc + vsw1, (bf16*)vl[(BS) ^ 1] + wv * 512);                   \
      gload16(vsrc + vsw2, (bf16*)vl[(BS) ^ 1] + 2048 + wv * 512);            \
      const _Float16* nA = bmrA + ((KT) + 1) * 64 + 8 * u;                    \
      const _Float16* nB = bmrB + ((KT) + 1) * 64 + 8 * u;                    \
      HN[0] = *(const f16x8*)(nA);                                            \
      HN[1] = *(const f16x8*)(nA + 32);                                       \
      HN[2] = *(const f16x8*)(nB);                                            \
      HN[3] = *(const f16x8*)(nB + 32);                                       \
    }                                                                         \
    float pA[16], pB[16];                                                     \
    _Pragma("unroll")                                                         \
    for (int f = 0; f < 4; ++f) {                                             \
      _Pragma("unroll")                                                       \
      for (int j = 0; j < 4; ++j) {                                           \
        float p = exp2a(sA[f][j] * C1_ + (float)HC[f & 1][4 * (f >> 1) + j]); \
        lsumA += p;                                                           \
        pA[f * 4 + j] = p;                                                    \
        float q2 = exp2a(sB[f][j] * C1_ +                                     \
                         (float)HC[2 + (f & 1)][4 * (f >> 1) + j]);           \
        lsumB += q2;                                                          \
        pB[f * 4 + j] = q2;                                                   \
      }                                                                       \
    }                                                                         \
    bf16x8 bpA0 = { (bf16)pA[0],  (bf16)pA[1],  (bf16)pA[2],  (bf16)pA[3],    \
                    (bf16)pA[8],  (bf16)pA[9],  (bf16)pA[10], (bf16)pA[11] }; \
    bf16x8 bpA1 = { (bf16)pA[4],  (bf16)pA[5],  (bf16)pA[6],  (bf16)pA[7],    \
                    (bf16)pA[12], (bf16)pA[13], (bf16)pA[14], (bf16)pA[15] }; \
    bf16x8 bpB0 = { (bf16)pB[0],  (bf16)pB[1],  (bf16)pB[2],  (bf16)pB[3],    \
                    (bf16)pB[8],  (bf16)pB[9],  (bf16)pB[10], (bf16)pB[11] }; \
    bf16x8 bpB1 = { (bf16)pB[4],  (bf16)pB[5],  (bf16)pB[6],  (bf16)pB[7],    \
                    (bf16)pB[12], (bf16)pB[13], (bf16)pB[14], (bf16)pB[15] }; \
    __builtin_amdgcn_s_setprio(1);                                            \
    _Pragma("unroll")                                                         \
    for (int g = 0; g < 4; ++g) {                                             \
      int rv = g * 16 + c;                                                    \
      int swv = rsw(rv);                                                      \
      bf16x8 v0 = *(const bf16x8*)&vl[BS][rv * 64 + ((u ^ swv) * 8)];         \
      bf16x8 v1 = *(const bf16x8*)&vl[BS][rv * 64 + (((4 + u) ^ swv) * 8)];   \
      accA[g] = mfma16(v0, bpA0, accA[g]);                                    \
      accA[g] = mfma16(v1, bpA1, accA[g]);                                    \
      accB[g] = mfma16(v0, bpB0, accB[g]);                                    \
      accB[g] = mfma16(v1, bpB1, accB[g]);                                    \
    }                                                                         \
    __builtin_amdgcn_s_setprio(0);                                            \
    __syncthreads();                                                          \
  }

__global__ __launch_bounds__(256) void k_pv(const bf16* __restrict__ Qw,
                                            const bf16* __restrict__ Kw,
                                            const bf16* __restrict__ Vtw,
                                            const _Float16* __restrict__ bmask,
                                            float* __restrict__ li_ws,
                                            bf16* __restrict__ valw) {
  __shared__ __align__(16) bf16 kl[2][64 * 64];   // K tile dbuf (8KB each)
  __shared__ __align__(16) bf16 vl[2][64 * 64];   // V tile dbuf (8KB each)
  const int tid = threadIdx.x, lane = tid & 63, wv = tid >> 6;  // wv 0..3
  const int u = lane >> 4, c = lane & 15;
  const int qt = blockIdx.x, h = blockIdx.y, b = blockIdx.z;
  const bf16* Qb = Qw + (size_t)(b * H_ + h) * S_ * HD_;
  const bf16* Kb = Kw + (size_t)(b * H_ + h) * S_ * HD_;
  const bf16* Vb = Vtw + (size_t)(b * H_ + h) * HD_ * S_;
  const int qrA = qt * 128 + wv * 32 + c;    // q-group A row
  const int qrB = qrA + 16;                  // q-group B row
  bf16x8 aqA0 = *(const bf16x8*)(Qb + (size_t)qrA * HD_ + u * 8);
  bf16x8 aqA1 = *(const bf16x8*)(Qb + (size_t)qrA * HD_ + 32 + u * 8);
  bf16x8 aqB0 = *(const bf16x8*)(Qb + (size_t)qrB * HD_ + u * 8);
  bf16x8 aqB1 = *(const bf16x8*)(Qb + (size_t)qrB * HD_ + 32 + u * 8);
  const _Float16* bmrA = bmask + (size_t)b * S_ * S_ + (size_t)qrA * S_;
  const _Float16* bmrB = bmask + (size_t)b * S_ * S_ + (size_t)qrB * S_;
  // staging: 256 threads, 2 granules each (g1 = tid, g2 = tid + 256)
  const int r1 = tid >> 3, s1 = (tid & 7) ^ rsw(tid >> 3);
  const int g2i = tid + 256;
  const int r2 = g2i >> 3, s2 = (g2i & 7) ^ rsw(g2i >> 3);
  const int ksw1 = (r1 * 8 + s1) * 8, ksw2 = (r2 * 8 + s2) * 8;
  const int vsw1 = r1 * S_ + s1 * 8, vsw2 = r2 * S_ + s2 * 8;
  // prologue: stage K,V tile 0; mask tile 0 into regs
  gload16(Kb + ksw1, (bf16*)kl[0] + wv * 512);
  gload16(Kb + ksw2, (bf16*)kl[0] + 2048 + wv * 512);
  gload16(Vb + vsw1, (bf16*)vl[0] + wv * 512);
  gload16(Vb + vsw2, (bf16*)vl[0] + 2048 + wv * 512);
  f16x8 hmA[4], hmB[4];
  hmA[0] = *(const f16x8*)(bmrA + 8 * u);
  hmA[1] = *(const f16x8*)(bmrA + 32 + 8 * u);
  hmA[2] = *(const f16x8*)(bmrB + 8 * u);
  hmA[3] = *(const f16x8*)(bmrB + 32 + 8 * u);
  f32x4 accA[4] = {}, accB[4] = {};
  float lsumA = 0.f, lsumB = 0.f;
  __syncthreads();
  for (int kt2 = 0; kt2 < 16; ++kt2) {
    PV_TILE2(hmA, hmB, 0, 2 * kt2, true);
    PV_TILE2(hmB, hmA, 1, 2 * kt2 + 1, (kt2 < 15));
  }
  // l: sum across the 4 u-lanes sharing each q-row
  lsumA += __shfl_xor(lsumA, 16, 64);
  lsumA += __shfl_xor(lsumA, 32, 64);
  lsumB += __shfl_xor(lsumB, 16, 64);
  lsumB += __shfl_xor(lsumB, 32, 64);
  float liA = 1.f / lsumA, liB = 1.f / lsumB;
  if (u == 0) {
    li_ws[(b * H_ + h) * S_ + qrA] = liA;
    li_ws[(b * H_ + h) * S_ + qrB] = liB;
  }
#pragma unroll
  for (int g = 0; g < 4; ++g) {
    bf16x4 pkA = { (bf16)(accA[g][0] * liA), (bf16)(accA[g][1] * liA),
                   (bf16)(accA[g][2] * liA), (bf16)(accA[g][3] * liA) };
    *(bf16x4*)(&valw[(size_t)(b * S_ + qrA) * E_ + h * HD_ + g * 16 + 4 * u]) = pkA;
    bf16x4 pkB = { (bf16)(accB[g][0] * liB), (bf16)(accB[g][1] * liB),
                   (bf16)(accB[g][2] * liB), (bf16)(accB[g][3] * liB) };
    *(bf16x4*)(&valw[(size_t)(b * S_ + qrB) * E_ + h * HD_ + g * 16 + 4 * u]) = pkB;
  }
}

// ---- attention_mean: 2 HEADS PER BARRIER-GROUP. 4 LDS K-bufs (32KB): group
// reads bufs {2p,2p+1}, stages next head-pair into the other two; ONE counted
// vmcnt(8) barrier per group (staging = 4 oldest gloads in flight; 8 Q-prefetch
// loads float across). Per-group work doubles vs per-head phases -> barrier
// stall amortized over 32 MFMA + 64 exp; h1's ds_reads interleave under h0's
// exp. kf regs reused across the two sub-phases to bound VGPR. ----
#define MEAN_GROUP(QC, QN, BS, HH, PF)                                         \
  {                                                                            \
    if (PF) {                                                                  \
      const bf16* ks0 = Kw + (size_t)(bh0 + (HH) + 2) * S_ * HD_ + ktoff;      \
      const bf16* ks1 = Kw + (size_t)(bh0 + (HH) + 3) * S_ * HD_ + ktoff;      \
      gload16(ks0 + sw1, (bf16*)kl2[2 * ((BS) ^ 1)] + wv * 512);               \
      gload16(ks0 + sw2, (bf16*)kl2[2 * ((BS) ^ 1)] + 2048 + wv * 512);        \
      gload16(ks1 + sw1, (bf16*)kl2[2 * ((BS) ^ 1) + 1] + wv * 512);           \
      gload16(ks1 + sw2, (bf16*)kl2[2 * ((BS) ^ 1) + 1] + 2048 + wv * 512);    \
      __builtin_amdgcn_sched_barrier(0);                                       \
    }                                                                          \
    /* head h0 = HH */                                                         \
    {                                                                          \
      bf16x8 kf[8];                                                            \
      _Pragma("unroll")                                                        \
      for (int f = 0; f < 4; ++f) {                                            \
        int row = f * 16 + c;                                                  \
        int sw = row & 7;                                                      \
        kf[2 * f]     = *(const bf16x8*)&kl2[2 * (BS)][row * 64 + ((u ^ sw) * 8)];\
        kf[2 * f + 1] = *(const bf16x8*)&kl2[2 * (BS)][row * 64 + (((4 + u) ^ sw) * 8)];\
      }                                                                        \
      if (PF) {                                                                \
        const bf16* Qn0 = Qw + (size_t)(bh0 + (HH) + 2) * S_ * HD_ + qoff;     \
        QN[0] = *(const bf16x8*)(Qn0);                                         \
        QN[1] = *(const bf16x8*)(Qn0 + 32);                                    \
        QN[2] = *(const bf16x8*)(Qn0 + 64 * HD_);                              \
        QN[3] = *(const bf16x8*)(Qn0 + 64 * HD_ + 32);                         \
      }                                                                        \
      float llA = li_l[(HH) * 128 + wv * 16 + c];                              \
      float llB = li_l[(HH) * 128 + 64 + wv * 16 + c];                         \
      _Pragma("unroll")                                                        \
      for (int f = 0; f < 4; ++f) {                                            \
        f32x4 a = {};                                                          \
        a = mfma16(kf[2 * f], QC[0], a);                                       \
        a = mfma16(kf[2 * f + 1], QC[1], a);                                   \
        f32x4 bb = {};                                                         \
        bb = mfma16(kf[2 * f], QC[2], bb);                                     \
        bb = mfma16(kf[2 * f + 1], QC[3], bb);                                 \
        _Pragma("unroll")                                                      \
        for (int j = 0; j < 4; ++j) {                                          \
          maccA[f][j] += exp2a(a[j] * C1_ + (float)mhA[f][j]) * llA;           \
          maccB[f][j] += exp2a(bb[j] * C1_ + (float)mhB[f][j]) * llB;          \
        }                                                                      \
      }                                                                        \
    }                                                                          \
    /* head h1 = HH+1 */                                                       \
    {                                                                          \
      bf16x8 kf[8];                                                            \
      _Pragma("unroll")                                                        \
      for (int f = 0; f < 4; ++f) {                                            \
        int row = f * 16 + c;                                                  \
        int sw = row & 7;                                                      \
        kf[2 * f]     = *(const bf16x8*)&kl2[2 * (BS) + 1][row * 64 + ((u ^ sw) * 8)];\
        kf[2 * f + 1] = *(const bf16x8*)&kl2[2 * (BS) + 1][row * 64 + (((4 + u) ^ sw) * 8)];\
      }                                                                        \
      if (PF) {                                                                \
        const bf16* Qn1 = Qw + (size_t)(bh0 + (HH) + 3) * S_ * HD_ + qoff;     \
        QN[4] = *(const bf16x8*)(Qn1);                                         \
        QN[5] = *(const bf16x8*)(Qn1 + 32);                                    \
        QN[6] = *(const bf16x8*)(Qn1 + 64 * HD_);                              \
        QN[7] = *(const bf16x8*)(Qn1 + 64 * HD_ + 32);                         \
      }                                                                        \
      float llA = li_l[((HH) + 1) * 128 + wv * 16 + c];                        \
      float llB = li_l[((HH) + 1) * 128 + 64 + wv * 16 + c];                   \
      _Pragma("unroll")                                                        \
      for (int f = 0; f < 4; ++f) {                                            \
        f32x4 a = {};                                                          \
        a = mfma16(kf[2 * f], QC[4], a);                                       \
        a = mfma16(kf[2 * f + 1], QC[5], a);                                   \
        f32x4 bb = {};                                                         \
        bb = mfma16(kf[2 * f], QC[6], bb);                                     \
        bb = mfma16(kf[2 * f + 1], QC[7], bb);                                 \
        _Pragma("unroll")                                                      \
        for (int j = 0; j < 4; ++j) {                                          \
          maccA[f][j] += exp2a(a[j] * C1_ + (float)mhA[f][j]) * llA;           \
          maccB[f][j] += exp2a(bb[j] * C1_ + (float)mhB[f][j]) * llB;          \
        }                                                                      \
      }                                                                        \
    }                                                                          \
    asm volatile("s_waitcnt vmcnt(8) lgkmcnt(0)" ::: "memory");                \
    __builtin_amdgcn_s_barrier();                                              \
  }

__global__ __launch_bounds__(256) void k_mean(const bf16* __restrict__ Qw,
                                              const bf16* __restrict__ Kw,
                                              const _Float16* __restrict__ bmask,
                                              const float* __restrict__ li_ws,
                                              float* __restrict__ mean_out) {
  __shared__ float li_l[H_ * 128];                // 8KB
  __shared__ __align__(16) bf16 kl2[4][64 * 64];  // 32KB, 4 bufs (pair dbuf)
  const int tid = threadIdx.x, lane = tid & 63, wv = tid >> 6;
  const int u = lane >> 4, c = lane & 15;
  const int qt = blockIdx.x, kt = blockIdx.y, b = blockIdx.z;
  const int bh0 = b * H_;
  for (int i = tid; i < H_ * 128; i += 256) {
    int hh = i >> 7, q = i & 127;
    li_l[i] = li_ws[(bh0 + hh) * S_ + qt * 128 + q];
  }
  const int qrow0 = qt * 128 + wv * 16;           // group A rows; B = +64
  const size_t ktoff = (size_t)kt * 64 * HD_;
  const size_t qoff = (size_t)(qrow0 + c) * HD_ + u * 8;
  f16x4 mhA[4], mhB[4];
  {
    const _Float16* bmpA = bmask + (size_t)b * S_ * S_ +
                           (size_t)(qrow0 + c) * S_ + (size_t)kt * 64 + 4 * u;
    const _Float16* bmpB = bmpA + (size_t)64 * S_;
#pragma unroll
    for (int f = 0; f < 4; ++f) {
      mhA[f] = *(const f16x4*)(bmpA + f * 16);
      mhB[f] = *(const f16x4*)(bmpB + f * 16);
    }
  }
  const int gg1 = wv * 64 + lane;
  const int gg2 = gg1 + 256;
  const int sw1 = (gg1 ^ ((gg1 >> 3) & 7)) * 8;
  const int sw2 = (gg2 ^ ((gg2 >> 3) & 7)) * 8;
  // prologue: stage K-tiles for heads 0,1 into bufs 0,1; Q for heads 0,1
  {
    const bf16* K0 = Kw + (size_t)bh0 * S_ * HD_ + ktoff;
    const bf16* K1 = Kw + (size_t)(bh0 + 1) * S_ * HD_ + ktoff;
    gload16(K0 + sw1, (bf16*)kl2[0] + wv * 512);
    gload16(K0 + sw2, (bf16*)kl2[0] + 2048 + wv * 512);
    gload16(K1 + sw1, (bf16*)kl2[1] + wv * 512);
    gload16(K1 + sw2, (bf16*)kl2[1] + 2048 + wv * 512);
  }
  bf16x8 qP[8], qN[8];
  {
    const bf16* Q0 = Qw + (size_t)bh0 * S_ * HD_ + qoff;
    const bf16* Q1 = Qw + (size_t)(bh0 + 1) * S_ * HD_ + qoff;
    qP[0] = *(const bf16x8*)Q0;
    qP[1] = *(const bf16x8*)(Q0 + 32);
    qP[2] = *(const bf16x8*)(Q0 + 64 * HD_);
    qP[3] = *(const bf16x8*)(Q0 + 64 * HD_ + 32);
    qP[4] = *(const bf16x8*)Q1;
    qP[5] = *(const bf16x8*)(Q1 + 32);
    qP[6] = *(const bf16x8*)(Q1 + 64 * HD_);
    qP[7] = *(const bf16x8*)(Q1 + 64 * HD_ + 32);
  }
  f32x4 maccA[4] = {}, maccB[4] = {};
  __syncthreads();
  for (int gg = 0; gg < 4; ++gg) {
    MEAN_GROUP(qP, qN, 0, 4 * gg, true);
    MEAN_GROUP(qN, qP, 1, 4 * gg + 2, (gg < 3));
  }
#pragma unroll
  for (int f = 0; f < 4; ++f) {
    f32x4 moA = maccA[f] * (1.f / 16.f);
    *(f32x4*)&mean_out[(size_t)b * S_ * S_ + (size_t)(qrow0 + c) * S_ +
                       (size_t)kt * 64 + f * 16 + 4 * u] = moA;
    f32x4 moB = maccB[f] * (1.f / 16.f);
    *(f32x4*)&mean_out[(size_t)b * S_ * S_ + (size_t)(qrow0 + 64 + c) * S_ +
                       (size_t)kt * 64 + f * 16 + 4 * u] = moB;
  }
}

// ---- output projection, m97 structure: out[8192,1024] = values * ow^T + ob ----
__global__ __launch_bounds__(256) void k_oproj(const bf16* __restrict__ vb,
                                               const bf16* __restrict__ wo,
                                               const float* __restrict__ ob,
                                               float* __restrict__ out) {
  __shared__ __align__(16) bf16 lA[128 * 32];
  __shared__ __align__(16) bf16 lB[128 * 32];
  const int tid = threadIdx.x, lane = tid & 63, wv = tid >> 6;
  const int u = lane >> 4, c = lane & 15;
  const int wr = wv >> 1, wc = wv & 1;
  const int m0 = blockIdx.y * 128;
  const int n0 = blockIdx.x * 128;
  const int sr = tid >> 2, sk = (tid & 3) * 8;
  const bf16* gA = vb + (size_t)(m0 + sr) * E_ + sk;
  const bf16* gB = wo + (size_t)(n0 + sr) * E_ + sk;
  bf16* lpA = lA + wv * 512;
  bf16* lpB = lB + wv * 512;
  f32x4 acc[4][4] = {};
  for (int k0 = 0; k0 < E_; k0 += 32) {
    gload16(gA + k0, lpA);
    gload16(gA + 64 * E_ + k0, lpA + 2048);
    gload16(gB + k0, lpB);
    gload16(gB + 64 * E_ + k0, lpB + 2048);
    __syncthreads();
    bf16x8 af[4], bfr[4];
#pragma unroll
    for (int m = 0; m < 4; ++m)
      af[m] = *(const bf16x8*)(lA + (wr * 64 + m * 16 + c) * 32 + u * 8);
#pragma unroll
    for (int n = 0; n < 4; ++n)
      bfr[n] = *(const bf16x8*)(lB + (wc * 64 + n * 16 + c) * 32 + u * 8);
#pragma unroll
    for (int m = 0; m < 4; ++m)
#pragma unroll
      for (int n = 0; n < 4; ++n)
        acc[m][n] = mfma16(af[m], bfr[n], acc[m][n]);
    __syncthreads();
  }
#pragma unroll
  for (int n = 0; n < 4; ++n) {
    int nn = n0 + wc * 64 + n * 16 + c;
    float bias = ob[nn];
#pragma unroll
    for (int m = 0; m < 4; ++m) {
#pragma unroll
      for (int r = 0; r < 4; ++r) {
        int q = m0 + wr * 64 + m * 16 + 4 * u + r;
        out[(size_t)q * E_ + nn] = acc[m][n][r] + bias;
      }
    }
  }
}

extern "C" void kernel_launch(void* const* d_in, const int* in_sizes, int n_in,
                              void* d_out, int out_size, void* d_ws, size_t ws_size,
                              hipStream_t stream) {
  const float* x    = (const float*)d_in[0];
  const float* mmsk = (const float*)d_in[2];
  const float* qkvw = (const float*)d_in[3];
  const float* qkvb = (const float*)d_in[4];
  const float* ow   = (const float*)d_in[5];
  const float* ob   = (const float*)d_in[6];

  char* ws = (char*)d_ws;
  bf16* xb  = (bf16*)(ws);                   // 16 MB; reused as values after k_qkv
  bf16* wb  = (bf16*)(ws + (16u << 20));     // 6 MB; dead after k_qkv -> li lives here
  bf16* owb = (bf16*)(ws + (22u << 20));     // 2 MB
  bf16* Qw  = (bf16*)(ws + (24u << 20));     // 16 MB
  bf16* Kw  = (bf16*)(ws + (40u << 20));     // 16 MB
  bf16* Vtw = (bf16*)(ws + (56u << 20));     // 16 MB   (total 72 MB)
  float* li_ws = (float*)(ws + (16u << 20)); // 512 KB (over dead wb)
  bf16* values = xb;

  float* out_o    = (float*)d_out;
  float* out_mean = out_o + (size_t)B_ * S_ * E_;
  // fp16 mask (prescaled by log2e) lives in out_o's 32 MB: written first,
  // consumed by k_pv + k_mean, then overwritten by k_oproj (same-stream order).
  _Float16* bmask = (_Float16*)out_o;

  k_cvt<<<dim3(2097152 / 256), 256, 0, stream>>>(x, xb, 2097152);
  k_cvt<<<dim3(786432 / 256), 256, 0, stream>>>(qkvw, wb, 786432);
  k_cvt<<<dim3(262144 / 256), 256, 0, stream>>>(ow, owb, 262144);
  k_cvt16<<<dim3(4194304 / 256), 256, 0, stream>>>(mmsk, bmask, 4194304);
  k_qkv<<<dim3(24, 64), 256, 0, stream>>>(xb, wb, qkvb, Qw, Kw, Vtw);
  k_pv<<<dim3(16, 16, 4), 256, 0, stream>>>(Qw, Kw, Vtw, bmask, li_ws, values);
  k_mean<<<dim3(16, 32, 4), 256, 0, stream>>>(Qw, Kw, bmask, li_ws, out_mean);
  k_oproj<<<dim3(8, 64), 256, 0, stream>>>(values, owb, ob, out_o);
}

// Round 7
// 331.136 us; speedup vs baseline: 1.0996x; 1.0996x over previous
//
#include <hip/hip_runtime.h>

#define B_ 4
#define S_ 2048
#define D_ 1024
#define E_ 1024
#define H_ 16
#define HD_ 64
#define SCALE 0.125f
#define LOG2E 1.44269504f
#define C1_ (SCALE * LOG2E)

typedef __bf16 bf16;
typedef __bf16 bf16x8 __attribute__((ext_vector_type(8)));
typedef __bf16 bf16x4 __attribute__((ext_vector_type(4)));
typedef float f32x4 __attribute__((ext_vector_type(4)));
typedef _Float16 f16x8 __attribute__((ext_vector_type(8)));
typedef _Float16 f16x4 __attribute__((ext_vector_type(4)));

static __device__ __forceinline__ f32x4 mfma16(bf16x8 a, bf16x8 b, f32x4 c) {
  return __builtin_amdgcn_mfma_f32_16x16x32_bf16(a, b, c, 0, 0, 0);
}

typedef __attribute__((address_space(3))) void lvoid;
typedef const __attribute__((address_space(1))) void gvoid;
static __device__ __forceinline__ void gload16(const void* g, void* l) {
  __builtin_amdgcn_global_load_lds((gvoid*)g, (lvoid*)l, 16, 0, 0);
}

// raw 2^x (input already scaled by log2e)
static __device__ __forceinline__ float exp2a(float x) {
  float r;
  asm("v_exp_f32 %0, %1" : "=v"(r) : "v"(x));
  return r;
}

// 3-bit row swizzle: spreads both natural and permuted row-reads over 8 slots
static __device__ __forceinline__ int rsw(int row) {
  return (row & 3) | (((row >> 3) & 1) << 2);
}

// ---- fused converts: one launch covers x->bf16, qkvw->bf16, ow->bf16,
// mask->fp16(prescaled by log2e). Block-range dispatch; every range is an
// exact multiple of 256 blocks so no bounds checks. Saves 3 launch gaps. ----
__global__ __launch_bounds__(256) void k_cvtall(const float* __restrict__ x, bf16* __restrict__ xb,
                                                const float* __restrict__ qkvw, bf16* __restrict__ wb,
                                                const float* __restrict__ ow, bf16* __restrict__ owb,
                                                const float* __restrict__ msk, _Float16* __restrict__ bm) {
  int bid = blockIdx.x;
  const float* src;
  int i;
  if (bid < 8192) {            // x: 2097152 float4
    i = bid * 256 + threadIdx.x;
    float4 v = reinterpret_cast<const float4*>(x)[i];
    bf16x4 o = { (bf16)v.x, (bf16)v.y, (bf16)v.z, (bf16)v.w };
    reinterpret_cast<bf16x4*>(xb)[i] = o;
  } else if (bid < 11264) {    // qkvw: 786432 float4
    i = (bid - 8192) * 256 + threadIdx.x;
    float4 v = reinterpret_cast<const float4*>(qkvw)[i];
    bf16x4 o = { (bf16)v.x, (bf16)v.y, (bf16)v.z, (bf16)v.w };
    reinterpret_cast<bf16x4*>(wb)[i] = o;
  } else if (bid < 12288) {    // ow: 262144 float4
    i = (bid - 11264) * 256 + threadIdx.x;
    float4 v = reinterpret_cast<const float4*>(ow)[i];
    bf16x4 o = { (bf16)v.x, (bf16)v.y, (bf16)v.z, (bf16)v.w };
    reinterpret_cast<bf16x4*>(owb)[i] = o;
  } else {                     // mask: 4194304 float4 -> fp16 * log2e
    i = (bid - 12288) * 256 + threadIdx.x;
    float4 v = reinterpret_cast<const float4*>(msk)[i];
    f16x4 o = { (_Float16)(v.x * LOG2E), (_Float16)(v.y * LOG2E),
                (_Float16)(v.z * LOG2E), (_Float16)(v.w * LOG2E) };
    reinterpret_cast<f16x4*>(bm)[i] = o;
  }
  (void)src;
}

// ---- QKV GEMM, m97 structure: 128x128 tile, LDS-staged via global_load_lds ----
__global__ __launch_bounds__(256) void k_qkv(const bf16* __restrict__ xb,
                                             const bf16* __restrict__ wb,
                                             const float* __restrict__ qkvb,
                                             bf16* __restrict__ Qw,
                                             bf16* __restrict__ Kw,
                                             bf16* __restrict__ Vtw) {
  __shared__ __align__(16) bf16 lA[128 * 32];
  __shared__ __align__(16) bf16 lB[128 * 32];
  const int tid = threadIdx.x, lane = tid & 63, wv = tid >> 6;
  const int u = lane >> 4, c = lane & 15;
  const int wr = wv >> 1, wc = wv & 1;
  const int m0 = blockIdx.y * 128;
  const int n0 = blockIdx.x * 128;
  const int sr = tid >> 2, sk = (tid & 3) * 8;
  const bf16* gA = xb + (size_t)(m0 + sr) * D_ + sk;
  const bf16* gB = wb + (size_t)(n0 + sr) * D_ + sk;
  bf16* lpA = lA + wv * 512;
  bf16* lpB = lB + wv * 512;
  f32x4 acc[4][4] = {};
  for (int k0 = 0; k0 < D_; k0 += 32) {
    gload16(gA + k0, lpA);
    gload16(gA + 64 * D_ + k0, lpA + 2048);
    gload16(gB + k0, lpB);
    gload16(gB + 64 * D_ + k0, lpB + 2048);
    __syncthreads();
    bf16x8 af[4], bfr[4];
#pragma unroll
    for (int m = 0; m < 4; ++m)
      af[m] = *(const bf16x8*)(lA + (wr * 64 + m * 16 + c) * 32 + u * 8);
#pragma unroll
    for (int n = 0; n < 4; ++n)
      bfr[n] = *(const bf16x8*)(lB + (wc * 64 + n * 16 + c) * 32 + u * 8);
#pragma unroll
    for (int m = 0; m < 4; ++m)
#pragma unroll
      for (int n = 0; n < 4; ++n)
        acc[m][n] = mfma16(af[m], bfr[n], acc[m][n]);
    __syncthreads();
  }
#pragma unroll
  for (int n = 0; n < 4; ++n) {
    int nn = n0 + wc * 64 + n * 16 + c;
    float bias = qkvb[nn];
    int h = nn / 192;
    int rem = nn - h * 192;
#pragma unroll
    for (int m = 0; m < 4; ++m) {
#pragma unroll
      for (int r = 0; r < 4; ++r) {
        int q = m0 + wr * 64 + m * 16 + 4 * u + r;
        int bb = q >> 11, s = q & 2047;
        bf16 v = (bf16)(acc[m][n][r] + bias);
        if (rem < 64)       Qw[((bb * H_ + h) * S_ + s) * HD_ + rem] = v;
        else if (rem < 128) Kw[((bb * H_ + h) * S_ + s) * HD_ + (rem - 64)] = v;
        else                Vtw[((bb * H_ + h) * HD_ + (rem - 128)) * S_ + s] = v;
      }
    }
  }
}

// ---- PV, swapped QK^T + permuted K rows. 4 waves x 2 q-groups (32 q-rows/wave)
// — exact R1 structure (proven 118 us): staging mid-tile, mask prefetch, exp,
// PV MFMAs, one __syncthreads per tile. 4 independent barrier domains per CU.
#define PV_TILE2(HC, HN, BS, KT, PF)                                          \
  {                                                                           \
    f32x4 sA[4], sB[4];                                                       \
    _Pragma("unroll")                                                         \
    for (int f = 0; f < 4; ++f) {                                             \
      int rk = 32 * (f & 1) + 8 * (c >> 2) + 4 * (f >> 1) + (c & 3);          \
      int sw = rsw(rk);                                                       \
      bf16x8 k0 = *(const bf16x8*)&kl[BS][rk * 64 + ((u ^ sw) * 8)];          \
      bf16x8 k1 = *(const bf16x8*)&kl[BS][rk * 64 + (((4 + u) ^ sw) * 8)];    \
      f32x4 a = {};                                                           \
      a = mfma16(k0, aqA0, a);                                                \
      a = mfma16(k1, aqA1, a);                                                \
      sA[f] = a;                                                              \
      f32x4 bb2 = {};                                                         \
      bb2 = mfma16(k0, aqB0, bb2);                                            \
      bb2 = mfma16(k1, aqB1, bb2);                                            \
      sB[f] = bb2;                                                            \
    }                                                                         \
    if (PF) {                                                                 \
      const bf16* ksrc = Kb + (size_t)((KT) + 1) * 64 * HD_;                  \
      gload16(ksrc + ksw1, (bf16*)kl[(BS) ^ 1] + wv * 512);                   \
      gload16(ksrc + ksw2, (bf16*)kl[(BS) ^ 1] + 2048 + wv * 512);            \
      const bf16* vsrc = Vb + (size_t)((KT) + 1) * 64;                        \
      gload16(vsrc + vsw1, (bf16*)vl[(BS) ^ 1] + wv * 512);                   \
      gload16(vsrc + vsw2, (bf16*)vl[(BS) ^ 1] + 2048 + wv * 512);            \
      const _Float16* nA = bmrA + ((KT) + 1) * 64 + 8 * u;                    \
      const _Float16* nB = bmrB + ((KT) + 1) * 64 + 8 * u;                    \
      HN[0] = *(const f16x8*)(nA);                                            \
      HN[1] = *(const f16x8*)(nA + 32);                                       \
      HN[2] = *(const f16x8*)(nB);                                            \
      HN[3] = *(const f16x8*)(nB + 32);                                       \
    }                                                                         \
    float pA[16], pB[16];                                                     \
    _Pragma("unroll")                                                         \
    for (int f = 0; f < 4; ++f) {                                             \
      _Pragma("unroll")                                                       \
      for (int j = 0; j < 4; ++j) {                                           \
        float p = exp2a(sA[f][j] * C1_ + (float)HC[f & 1][4 * (f >> 1) + j]); \
        lsumA += p;                                                           \
        pA[f * 4 + j] = p;                                                    \
        float q2 = exp2a(sB[f][j] * C1_ +                                     \
                         (float)HC[2 + (f & 1)][4 * (f >> 1) + j]);           \
        lsumB += q2;                                                          \
        pB[f * 4 + j] = q2;                                                   \
      }                                                                       \
    }                                                                         \
    bf16x8 bpA0 = { (bf16)pA[0],  (bf16)pA[1],  (bf16)pA[2],  (bf16)pA[3],    \
                    (bf16)pA[8],  (bf16)pA[9],  (bf16)pA[10], (bf16)pA[11] }; \
    bf16x8 bpA1 = { (bf16)pA[4],  (bf16)pA[5],  (bf16)pA[6],  (bf16)pA[7],    \
                    (bf16)pA[12], (bf16)pA[13], (bf16)pA[14], (bf16)pA[15] }; \
    bf16x8 bpB0 = { (bf16)pB[0],  (bf16)pB[1],  (bf16)pB[2],  (bf16)pB[3],    \
                    (bf16)pB[8],  (bf16)pB[9],  (bf16)pB[10], (bf16)pB[11] }; \
    bf16x8 bpB1 = { (bf16)pB[4],  (bf16)pB[5],  (bf16)pB[6],  (bf16)pB[7],    \
                    (bf16)pB[12], (bf16)pB[13], (bf16)pB[14], (bf16)pB[15] }; \
    __builtin_amdgcn_s_setprio(1);                                            \
    _Pragma("unroll")                                                         \
    for (int g = 0; g < 4; ++g) {                                             \
      int rv = g * 16 + c;                                                    \
      int swv = rsw(rv);                                                      \
      bf16x8 v0 = *(const bf16x8*)&vl[BS][rv * 64 + ((u ^ swv) * 8)];         \
      bf16x8 v1 = *(const bf16x8*)&vl[BS][rv * 64 + (((4 + u) ^ swv) * 8)];   \
      accA[g] = mfma16(v0, bpA0, accA[g]);                                    \
      accA[g] = mfma16(v1, bpA1, accA[g]);                                    \
      accB[g] = mfma16(v0, bpB0, accB[g]);                                    \
      accB[g] = mfma16(v1, bpB1, accB[g]);                                    \
    }                                                                         \
    __builtin_amdgcn_s_setprio(0);                                            \
    __syncthreads();                                                          \
  }

__global__ __launch_bounds__(256) void k_pv(const bf16* __restrict__ Qw,
                                            const bf16* __restrict__ Kw,
                                            const bf16* __restrict__ Vtw,
                                            const _Float16* __restrict__ bmask,
                                            float* __restrict__ li_ws,
                                            bf16* __restrict__ valw) {
  __shared__ __align__(16) bf16 kl[2][64 * 64];   // K tile dbuf (8KB each)
  __shared__ __align__(16) bf16 vl[2][64 * 64];   // V tile dbuf (8KB each)
  const int tid = threadIdx.x, lane = tid & 63, wv = tid >> 6;  // wv 0..3
  const int u = lane >> 4, c = lane & 15;
  const int qt = blockIdx.x, h = blockIdx.y, b = blockIdx.z;
  const bf16* Qb = Qw + (size_t)(b * H_ + h) * S_ * HD_;
  const bf16* Kb = Kw + (size_t)(b * H_ + h) * S_ * HD_;
  const bf16* Vb = Vtw + (size_t)(b * H_ + h) * HD_ * S_;
  const int qrA = qt * 128 + wv * 32 + c;    // q-group A row
  const int qrB = qrA + 16;                  // q-group B row
  bf16x8 aqA0 = *(const bf16x8*)(Qb + (size_t)qrA * HD_ + u * 8);
  bf16x8 aqA1 = *(const bf16x8*)(Qb + (size_t)qrA * HD_ + 32 + u * 8);
  bf16x8 aqB0 = *(const bf16x8*)(Qb + (size_t)qrB * HD_ + u * 8);
  bf16x8 aqB1 = *(const bf16x8*)(Qb + (size_t)qrB * HD_ + 32 + u * 8);
  const _Float16* bmrA = bmask + (size_t)b * S_ * S_ + (size_t)qrA * S_;
  const _Float16* bmrB = bmask + (size_t)b * S_ * S_ + (size_t)qrB * S_;
  // staging: 256 threads, 2 granules each (g1 = tid, g2 = tid + 256)
  const int r1 = tid >> 3, s1 = (tid & 7) ^ rsw(tid >> 3);
  const int g2i = tid + 256;
  const int r2 = g2i >> 3, s2 = (g2i & 7) ^ rsw(g2i >> 3);
  const int ksw1 = (r1 * 8 + s1) * 8, ksw2 = (r2 * 8 + s2) * 8;
  const int vsw1 = r1 * S_ + s1 * 8, vsw2 = r2 * S_ + s2 * 8;
  // prologue: stage K,V tile 0; mask tile 0 into regs
  gload16(Kb + ksw1, (bf16*)kl[0] + wv * 512);
  gload16(Kb + ksw2, (bf16*)kl[0] + 2048 + wv * 512);
  gload16(Vb + vsw1, (bf16*)vl[0] + wv * 512);
  gload16(Vb + vsw2, (bf16*)vl[0] + 2048 + wv * 512);
  f16x8 hmA[4], hmB[4];
  hmA[0] = *(const f16x8*)(bmrA + 8 * u);
  hmA[1] = *(const f16x8*)(bmrA + 32 + 8 * u);
  hmA[2] = *(const f16x8*)(bmrB + 8 * u);
  hmA[3] = *(const f16x8*)(bmrB + 32 + 8 * u);
  f32x4 accA[4] = {}, accB[4] = {};
  float lsumA = 0.f, lsumB = 0.f;
  __syncthreads();
  for (int kt2 = 0; kt2 < 16; ++kt2) {
    PV_TILE2(hmA, hmB, 0, 2 * kt2, true);
    PV_TILE2(hmB, hmA, 1, 2 * kt2 + 1, (kt2 < 15));
  }
  // l: sum across the 4 u-lanes sharing each q-row
  lsumA += __shfl_xor(lsumA, 16, 64);
  lsumA += __shfl_xor(lsumA, 32, 64);
  lsumB += __shfl_xor(lsumB, 16, 64);
  lsumB += __shfl_xor(lsumB, 32, 64);
  float liA = 1.f / lsumA, liB = 1.f / lsumB;
  if (u == 0) {
    li_ws[(b * H_ + h) * S_ + qrA] = liA;
    li_ws[(b * H_ + h) * S_ + qrB] = liB;
  }
#pragma unroll
  for (int g = 0; g < 4; ++g) {
    bf16x4 pkA = { (bf16)(accA[g][0] * liA), (bf16)(accA[g][1] * liA),
                   (bf16)(accA[g][2] * liA), (bf16)(accA[g][3] * liA) };
    *(bf16x4*)(&valw[(size_t)(b * S_ + qrA) * E_ + h * HD_ + g * 16 + 4 * u]) = pkA;
    bf16x4 pkB = { (bf16)(accB[g][0] * liB), (bf16)(accB[g][1] * liB),
                   (bf16)(accB[g][2] * liB), (bf16)(accB[g][3] * liB) };
    *(bf16x4*)(&valw[(size_t)(b * S_ + qrB) * E_ + h * HD_ + g * 16 + 4 * u]) = pkB;
  }
}

// ---- attention_mean: swapped QK^T, 4 waves x 2 q-groups (q-tile 128): the 8
// K-frag ds_reads + tile staging serve 2x the work. Stage-early + counted
// vmcnt(4) barrier per phase (newest 4 = Q reg-prefetch loads float across
// the barrier; staging loads guaranteed landed). Proven best (~105 us across
// R2/R5). Mask in f16 regs; li in LDS. ----
#define MEAN_PHASE(QC0, QC1, QC2, QC3, QN0, QN1, QN2, QN3, BS, HH, PF)         \
  {                                                                            \
    if (PF) {                                                                  \
      const bf16* ksrc = Kw + (size_t)(bh0 + (HH) + 1) * S_ * HD_ +            \
                         (size_t)kt * 64 * HD_;                                \
      gload16(ksrc + sw1, (bf16*)kl2[(BS) ^ 1] + wv * 512);                    \
      gload16(ksrc + sw2, (bf16*)kl2[(BS) ^ 1] + 2048 + wv * 512);             \
      __builtin_amdgcn_sched_barrier(0);                                       \
    }                                                                          \
    bf16x8 kf[8];                                                              \
    _Pragma("unroll")                                                          \
    for (int f = 0; f < 4; ++f) {                                              \
      int row = f * 16 + c;                                                    \
      int sw = row & 7;                                                        \
      kf[2 * f]     = *(const bf16x8*)&kl2[BS][row * 64 + ((u ^ sw) * 8)];     \
      kf[2 * f + 1] = *(const bf16x8*)&kl2[BS][row * 64 + (((4 + u) ^ sw) * 8)];\
    }                                                                          \
    if (PF) {                                                                  \
      const bf16* Qn = Qw + (size_t)(bh0 + (HH) + 1) * S_ * HD_ +              \
                       (size_t)(qrow0 + c) * HD_ + u * 8;                      \
      QN0 = *(const bf16x8*)(Qn);                                              \
      QN1 = *(const bf16x8*)(Qn + 32);                                         \
      QN2 = *(const bf16x8*)(Qn + 64 * HD_);                                   \
      QN3 = *(const bf16x8*)(Qn + 64 * HD_ + 32);                              \
    }                                                                          \
    float llA = li_l[(HH) * 128 + wv * 16 + c];                                \
    float llB = li_l[(HH) * 128 + 64 + wv * 16 + c];                           \
    _Pragma("unroll")                                                          \
    for (int f = 0; f < 4; ++f) {                                              \
      f32x4 a = {};                                                            \
      a = mfma16(kf[2 * f], QC0, a);                                           \
      a = mfma16(kf[2 * f + 1], QC1, a);                                       \
      f32x4 bb = {};                                                           \
      bb = mfma16(kf[2 * f], QC2, bb);                                         \
      bb = mfma16(kf[2 * f + 1], QC3, bb);                                     \
      _Pragma("unroll")                                                        \
      for (int j = 0; j < 4; ++j) {                                            \
        maccA[f][j] += exp2a(a[j] * C1_ + (float)mhA[f][j]) * llA;             \
        maccB[f][j] += exp2a(bb[j] * C1_ + (float)mhB[f][j]) * llB;            \
      }                                                                        \
    }                                                                          \
    asm volatile("s_waitcnt vmcnt(4) lgkmcnt(0)" ::: "memory");                \
    __builtin_amdgcn_s_barrier();                                              \
  }

__global__ __launch_bounds__(256) void k_mean(const bf16* __restrict__ Qw,
                                              const bf16* __restrict__ Kw,
                                              const _Float16* __restrict__ bmask,
                                              const float* __restrict__ li_ws,
                                              float* __restrict__ mean_out) {
  __shared__ float li_l[H_ * 128];                // 8KB
  __shared__ __align__(16) bf16 kl2[2][64 * 64];  // 16KB
  const int tid = threadIdx.x, lane = tid & 63, wv = tid >> 6;
  const int u = lane >> 4, c = lane & 15;
  const int qt = blockIdx.x, kt = blockIdx.y, b = blockIdx.z;
  const int bh0 = b * H_;
  for (int i = tid; i < H_ * 128; i += 256) {
    int hh = i >> 7, q = i & 127;
    li_l[i] = li_ws[(bh0 + hh) * S_ + qt * 128 + q];
  }
  const int qrow0 = qt * 128 + wv * 16;           // group A rows; B = +64
  f16x4 mhA[4], mhB[4];
  {
    const _Float16* bmpA = bmask + (size_t)b * S_ * S_ +
                           (size_t)(qrow0 + c) * S_ + (size_t)kt * 64 + 4 * u;
    const _Float16* bmpB = bmpA + (size_t)64 * S_;
#pragma unroll
    for (int f = 0; f < 4; ++f) {
      mhA[f] = *(const f16x4*)(bmpA + f * 16);
      mhB[f] = *(const f16x4*)(bmpB + f * 16);
    }
  }
  const int gg1 = wv * 64 + lane;
  const int gg2 = gg1 + 256;
  const int sw1 = (gg1 ^ ((gg1 >> 3) & 7)) * 8;
  const int sw2 = (gg2 ^ ((gg2 >> 3) & 7)) * 8;
  {
    const bf16* K0 = Kw + (size_t)bh0 * S_ * HD_ + (size_t)kt * 64 * HD_;
    gload16(K0 + sw1, (bf16*)kl2[0] + wv * 512);
    gload16(K0 + sw2, (bf16*)kl2[0] + 2048 + wv * 512);
  }
  bf16x8 qA0, qA1, qA2, qA3, qB0, qB1, qB2, qB3;
  {
    const bf16* Q0 = Qw + (size_t)bh0 * S_ * HD_ + (size_t)(qrow0 + c) * HD_ + u * 8;
    qA0 = *(const bf16x8*)Q0;
    qA1 = *(const bf16x8*)(Q0 + 32);
    qA2 = *(const bf16x8*)(Q0 + 64 * HD_);
    qA3 = *(const bf16x8*)(Q0 + 64 * HD_ + 32);
  }
  f32x4 maccA[4] = {}, maccB[4] = {};
  __syncthreads();
  for (int h2 = 0; h2 < 8; ++h2) {
    MEAN_PHASE(qA0, qA1, qA2, qA3, qB0, qB1, qB2, qB3, 0, 2 * h2, true);
    MEAN_PHASE(qB0, qB1, qB2, qB3, qA0, qA1, qA2, qA3, 1, 2 * h2 + 1, (h2 < 7));
  }
#pragma unroll
  for (int f = 0; f < 4; ++f) {
    f32x4 moA = maccA[f] * (1.f / 16.f);
    *(f32x4*)&mean_out[(size_t)b * S_ * S_ + (size_t)(qrow0 + c) * S_ +
                       (size_t)kt * 64 + f * 16 + 4 * u] = moA;
    f32x4 moB = maccB[f] * (1.f / 16.f);
    *(f32x4*)&mean_out[(size_t)b * S_ * S_ + (size_t)(qrow0 + 64 + c) * S_ +
                       (size_t)kt * 64 + f * 16 + 4 * u] = moB;
  }
}

// ---- output projection, m97 structure: out[8192,1024] = values * ow^T + ob ----
__global__ __launch_bounds__(256) void k_oproj(const bf16* __restrict__ vb,
                                               const bf16* __restrict__ wo,
                                               const float* __restrict__ ob,
                                               float* __restrict__ out) {
  __shared__ __align__(16) bf16 lA[128 * 32];
  __shared__ __align__(16) bf16 lB[128 * 32];
  const int tid = threadIdx.x, lane = tid & 63, wv = tid >> 6;
  const int u = lane >> 4, c = lane & 15;
  const int wr = wv >> 1, wc = wv & 1;
  const int m0 = blockIdx.y * 128;
  const int n0 = blockIdx.x * 128;
  const int sr = tid >> 2, sk = (tid & 3) * 8;
  const bf16* gA = vb + (size_t)(m0 + sr) * E_ + sk;
  const bf16* gB = wo + (size_t)(n0 + sr) * E_ + sk;
  bf16* lpA = lA + wv * 512;
  bf16* lpB = lB + wv * 512;
  f32x4 acc[4][4] = {};
  for (int k0 = 0; k0 < E_; k0 += 32) {
    gload16(gA + k0, lpA);
    gload16(gA + 64 * E_ + k0, lpA + 2048);
    gload16(gB + k0, lpB);
    gload16(gB + 64 * E_ + k0, lpB + 2048);
    __syncthreads();
    bf16x8 af[4], bfr[4];
#pragma unroll
    for (int m = 0; m < 4; ++m)
      af[m] = *(const bf16x8*)(lA + (wr * 64 + m * 16 + c) * 32 + u * 8);
#pragma unroll
    for (int n = 0; n < 4; ++n)
      bfr[n] = *(const bf16x8*)(lB + (wc * 64 + n * 16 + c) * 32 + u * 8);
#pragma unroll
    for (int m = 0; m < 4; ++m)
#pragma unroll
      for (int n = 0; n < 4; ++n)
        acc[m][n] = mfma16(af[m], bfr[n], acc[m][n]);
    __syncthreads();
  }
#pragma unroll
  for (int n = 0; n < 4; ++n) {
    int nn = n0 + wc * 64 + n * 16 + c;
    float bias = ob[nn];
#pragma unroll
    for (int m = 0; m < 4; ++m) {
#pragma unroll
      for (int r = 0; r < 4; ++r) {
        int q = m0 + wr * 64 + m * 16 + 4 * u + r;
        out[(size_t)q * E_ + nn] = acc[m][n][r] + bias;
      }
    }
  }
}

extern "C" void kernel_launch(void* const* d_in, const int* in_sizes, int n_in,
                              void* d_out, int out_size, void* d_ws, size_t ws_size,
                              hipStream_t stream) {
  const float* x    = (const float*)d_in[0];
  const float* mmsk = (const float*)d_in[2];
  const float* qkvw = (const float*)d_in[3];
  const float* qkvb = (const float*)d_in[4];
  const float* ow   = (const float*)d_in[5];
  const float* ob   = (const float*)d_in[6];

  char* ws = (char*)d_ws;
  bf16* xb  = (bf16*)(ws);                   // 16 MB; reused as values after k_qkv
  bf16* wb  = (bf16*)(ws + (16u << 20));     // 6 MB; dead after k_qkv -> li lives here
  bf16* owb = (bf16*)(ws + (22u << 20));     // 2 MB
  bf16* Qw  = (bf16*)(ws + (24u << 20));     // 16 MB
  bf16* Kw  = (bf16*)(ws + (40u << 20));     // 16 MB
  bf16* Vtw = (bf16*)(ws + (56u << 20));     // 16 MB   (total 72 MB)
  float* li_ws = (float*)(ws + (16u << 20)); // 512 KB (over dead wb)
  bf16* values = xb;

  float* out_o    = (float*)d_out;
  float* out_mean = out_o + (size_t)B_ * S_ * E_;
  // fp16 mask (prescaled by log2e) lives in out_o's 32 MB: written first,
  // consumed by k_pv + k_mean, then overwritten by k_oproj (same-stream order).
  _Float16* bmask = (_Float16*)out_o;

  k_cvtall<<<dim3(28672), 256, 0, stream>>>(x, xb, qkvw, wb, ow, owb, mmsk, bmask);
  k_qkv<<<dim3(24, 64), 256, 0, stream>>>(xb, wb, qkvb, Qw, Kw, Vtw);
  k_pv<<<dim3(16, 16, 4), 256, 0, stream>>>(Qw, Kw, Vtw, bmask, li_ws, values);
  k_mean<<<dim3(16, 32, 4), 256, 0, stream>>>(Qw, Kw, bmask, li_ws, out_mean);
  k_oproj<<<dim3(8, 64), 256, 0, stream>>>(values, owb, ob, out_o);
}